// Round 2
// baseline (1176.834 us; speedup 1.0000x reference)
//
#include <hip/hip_runtime.h>
#include <hip/hip_bf16.h>

typedef __attribute__((ext_vector_type(4))) float f32x4;
typedef __attribute__((ext_vector_type(8))) short bf16x8;
typedef __attribute__((ext_vector_type(4))) int i32x4;

#define BM 128
#define BN 128
#define BK 64
#define PK 72   // padded LDS row stride in shorts (144 B = 9*16, keeps b128 alignment)
#define GS 128

__device__ __forceinline__ short f2bf(float f) {
    union { float f; unsigned u; } v; v.f = f;
    unsigned r = v.u + 0x7fffu + ((v.u >> 16) & 1u);
    return (short)(r >> 16);
}

__global__ void gptq_gemm_kernel(const float* __restrict__ X,
                                 const int* __restrict__ QW,
                                 const float* __restrict__ SC,
                                 const int* __restrict__ ZR,
                                 const float* __restrict__ BI,
                                 float* __restrict__ Y,
                                 int M, int N, int K, int G) {
    __shared__ __align__(16) short As[BM * PK];
    __shared__ __align__(16) short Bs[BN * PK];

    const int tid = threadIdx.x;
    const int nbm = M / BM;
    const int bid = blockIdx.x;
    const int cpx = gridDim.x >> 3;
    const int wgid = (bid & 7) * cpx + (bid >> 3);   // bijective XCD swizzle (grid%8==0)
    const int tm = wgid % nbm;                        // consecutive wgids share N-panel
    const int tn = wgid / nbm;
    const long m0 = (long)tm * BM;
    const long n0 = (long)tn * BN;
    const int Kp = K >> 1;

    const int lane = tid & 63;
    const int wid = tid >> 6;
    const int wr = wid >> 1;
    const int wc = wid & 1;
    const int fr = lane & 15;
    const int fq = lane >> 4;

    // staging decomposition: chunk c -> (row, k-chunk) of the 128x64 tile
    int srow[4], sq[4];
#pragma unroll
    for (int c = 0; c < 4; ++c) {
        int w = tid + 256 * c;
        srow[c] = w >> 3;       // 0..127
        sq[c] = w & 7;          // k0 = 8*sq
    }

    f32x4 acc[4][4] = {};
    const int NT = K / BK;

    for (int kt = 0; kt < NT; ++kt) {
        const int g = (kt * BK) / GS;   // whole tile in one quant group (64 | 128)

        f32x4 a0[4], a1[4];
        i32x4 b4[4];
        float sc_r[4], zr_r[4];
#pragma unroll
        for (int c = 0; c < 4; ++c) {
            const float* pa = X + (m0 + srow[c]) * K + kt * BK + 8 * sq[c];
            a0[c] = *(const f32x4*)pa;
            a1[c] = *(const f32x4*)(pa + 4);
            const int* pb = QW + (n0 + srow[c]) * Kp + kt * (BK / 2) + 4 * sq[c];
            b4[c] = *(const i32x4*)pb;
            sc_r[c] = SC[(n0 + srow[c]) * G + g];
            zr_r[c] = (float)ZR[(n0 + srow[c]) * G + g];
        }

        __syncthreads();   // previous tile's LDS reads complete
#pragma unroll
        for (int c = 0; c < 4; ++c) {
            bf16x8 av;
#pragma unroll
            for (int i = 0; i < 4; ++i) av[i] = f2bf(a0[c][i]);
#pragma unroll
            for (int i = 0; i < 4; ++i) av[4 + i] = f2bf(a1[c][i]);
            *(bf16x8*)(As + srow[c] * PK + 8 * sq[c]) = av;

            bf16x8 bv;
            const float s = sc_r[c], z = zr_r[c];
#pragma unroll
            for (int j = 0; j < 4; ++j) {
                int v = b4[c][j];
                bv[2 * j]     = f2bf(((float)(v & 15) - z) * s);
                bv[2 * j + 1] = f2bf(((float)((v >> 4) & 15) - z) * s);
            }
            *(bf16x8*)(Bs + srow[c] * PK + 8 * sq[c]) = bv;
        }
        __syncthreads();   // staged data visible

#pragma unroll
        for (int kk = 0; kk < BK; kk += 32) {
            bf16x8 a[4], b[4];
#pragma unroll
            for (int mf = 0; mf < 4; ++mf)
                a[mf] = *(const bf16x8*)(As + (wr * 64 + mf * 16 + fr) * PK + kk + 8 * fq);
#pragma unroll
            for (int nf = 0; nf < 4; ++nf)
                b[nf] = *(const bf16x8*)(Bs + (wc * 64 + nf * 16 + fr) * PK + kk + 8 * fq);
#pragma unroll
            for (int mf = 0; mf < 4; ++mf)
#pragma unroll
                for (int nf = 0; nf < 4; ++nf)
                    acc[mf][nf] = __builtin_amdgcn_mfma_f32_16x16x32_bf16(
                        a[mf], b[nf], acc[mf][nf], 0, 0, 0);
        }
    }

    // epilogue: C/D layout col=lane&15, row=4*(lane>>4)+i  [measured m89/m91]
#pragma unroll
    for (int nf = 0; nf < 4; ++nf) {
        const long col = n0 + wc * 64 + nf * 16 + fr;
        const float bias_v = BI[col];
#pragma unroll
        for (int mf = 0; mf < 4; ++mf) {
            const long rbase = m0 + wr * 64 + mf * 16 + 4 * fq;
#pragma unroll
            for (int i = 0; i < 4; ++i)
                Y[(rbase + i) * N + col] = acc[mf][nf][i] + bias_v;
        }
    }
}

extern "C" void kernel_launch(void* const* d_in, const int* in_sizes, int n_in,
                              void* d_out, int out_size, void* d_ws, size_t ws_size,
                              hipStream_t stream) {
    const float* X = (const float*)d_in[0];
    const int* QW = (const int*)d_in[1];
    const float* SC = (const float*)d_in[2];
    const int* ZR = (const int*)d_in[3];
    const float* BI = (const float*)d_in[4];
    float* Y = (float*)d_out;

    const int N = in_sizes[4];          // 4096
    const int G = in_sizes[2] / N;      // 32
    const int K = G * GS;               // 4096
    const int M = in_sizes[0] / K;      // 8192

    const int grid = (M / BM) * (N / BN);   // 2048, % 8 == 0
    hipLaunchKernelGGL(gptq_gemm_kernel, dim3(grid), dim3(256), 0, stream,
                       X, QW, SC, ZR, BI, Y, M, N, K, G);
}

// Round 3
// 381.309 us; speedup vs baseline: 3.0863x; 3.0863x over previous
//
#include <hip/hip_runtime.h>
#include <hip/hip_bf16.h>

typedef __attribute__((ext_vector_type(4))) float f32x4;
typedef __attribute__((ext_vector_type(8))) short bf16x8;
typedef __attribute__((ext_vector_type(4))) int i32x4;

#define BM 128
#define BN 128
#define BK 64
#define PK 72
#define GS 128

#define GLOAD_LDS16(g, l)                                                        \
    __builtin_amdgcn_global_load_lds(                                            \
        (const __attribute__((address_space(1))) void*)(g),                      \
        (__attribute__((address_space(3))) void*)(l), 16, 0, 0)

__device__ __forceinline__ short f2bf(float f) {
    union { float f; unsigned u; } v; v.f = f;
    unsigned r = v.u + 0x7fffu + ((v.u >> 16) & 1u);
    return (short)(r >> 16);
}

__device__ __forceinline__ bf16x8 dq8(int q0, int q1, int q2, int q3, float s, float z) {
    bf16x8 r;
    int q[4] = {q0, q1, q2, q3};
#pragma unroll
    for (int j = 0; j < 4; ++j) {
        r[2 * j]     = f2bf(((float)(q[j] & 15) - z) * s);
        r[2 * j + 1] = f2bf(((float)((q[j] >> 4) & 15) - z) * s);
    }
    return r;
}

// ---------------- prep: dequant W -> bf16 (N x K row-major) ----------------
__global__ void dequant_w_kernel(const int* __restrict__ QW,
                                 const float* __restrict__ SC,
                                 const int* __restrict__ ZR,
                                 short* __restrict__ W, int K, int G) {
    const int cpr = K / 32;                       // 32-k chunks per row
    const int t = blockIdx.x * blockDim.x + threadIdx.x;
    const int o = t / cpr;
    const int c = t % cpr;
    const int g = (c * 32) / GS;
    const float s = SC[(long)o * G + g];
    const float z = (float)ZR[(long)o * G + g];
    const int* p = QW + (long)o * (K / 2) + c * 16;
    i32x4 v0 = *(const i32x4*)p;
    i32x4 v1 = *(const i32x4*)(p + 4);
    i32x4 v2 = *(const i32x4*)(p + 8);
    i32x4 v3 = *(const i32x4*)(p + 12);
    short* out = W + (long)o * K + c * 32;
    *(bf16x8*)(out)      = dq8(v0[0], v0[1], v0[2], v0[3], s, z);
    *(bf16x8*)(out + 8)  = dq8(v1[0], v1[1], v1[2], v1[3], s, z);
    *(bf16x8*)(out + 16) = dq8(v2[0], v2[1], v2[2], v2[3], s, z);
    *(bf16x8*)(out + 24) = dq8(v3[0], v3[1], v3[2], v3[3], s, z);
}

// ---------------- prep: convert X fp32 -> bf16 ----------------
__global__ void cvt_x_kernel(const float* __restrict__ X, short* __restrict__ Xb, long n) {
    long i = ((long)blockIdx.x * blockDim.x + threadIdx.x) * 8;
    const long stride = (long)gridDim.x * blockDim.x * 8;
    for (; i < n; i += stride) {
        f32x4 a = *(const f32x4*)(X + i);
        f32x4 b = *(const f32x4*)(X + i + 4);
        bf16x8 o;
#pragma unroll
        for (int j = 0; j < 4; ++j) { o[j] = f2bf(a[j]); o[4 + j] = f2bf(b[j]); }
        *(bf16x8*)(Xb + i) = o;
    }
}

// ---------------- main: bf16 GEMM, m97 structure (global_load_lds) ----------------
__global__ void gemm_bf16_kernel(const short* __restrict__ A,   // M x K bf16
                                 const short* __restrict__ B,   // N x K bf16 (W)
                                 const float* __restrict__ BI,
                                 float* __restrict__ Y,
                                 int M, int N, int K) {
    __shared__ __align__(16) short As[BM * BK];
    __shared__ __align__(16) short Bs[BN * BK];

    const int tid = threadIdx.x;
    const int nbm = M / BM;
    const int bid = blockIdx.x;
    const int cpx = gridDim.x >> 3;
    const int wgid = (bid & 7) * cpx + (bid >> 3);   // bijective XCD swizzle (grid%8==0)
    const int tm = wgid % nbm;                        // consecutive wgids share W-panel
    const int tn = wgid / nbm;
    const long m0 = (long)tm * BM;
    const long n0 = (long)tn * BN;

    const int lane = tid & 63;
    const int wid = tid >> 6;
    const int wr = wid >> 1;
    const int wc = wid & 1;
    const int fr = lane & 15;
    const int fq = lane >> 4;

    // staging: issue i covers tile rows [i*32, i*32+32); wave w owns 8 rows.
    const int strow = wid * 8 + (lane >> 3);          // row within 32-row slab
    const int skcol = (lane & 7) * 8;                 // k-offset (8 bf16 = 16B)
    const short* ga = A + (m0 + strow) * (long)K + skcol;
    const short* gb = B + (n0 + strow) * (long)K + skcol;
    short* lA = As + wid * 512;                       // wave-uniform LDS base
    short* lB = Bs + wid * 512;

    f32x4 acc[4][4] = {};
    const int NT = K / BK;

    for (int kt = 0; kt < NT; ++kt) {
        const long kbase = (long)kt * BK;
#pragma unroll
        for (int i = 0; i < 4; ++i) {
            GLOAD_LDS16(ga + kbase + (long)i * 32 * K, lA + i * 2048);
            GLOAD_LDS16(gb + kbase + (long)i * 32 * K, lB + i * 2048);
        }
        asm volatile("s_waitcnt vmcnt(0)" ::: "memory");
        __syncthreads();

#pragma unroll
        for (int kk = 0; kk < BK; kk += 32) {
            bf16x8 a[4], b[4];
#pragma unroll
            for (int mf = 0; mf < 4; ++mf)
                a[mf] = *(const bf16x8*)(As + (wr * 64 + mf * 16 + fr) * BK + kk + 8 * fq);
#pragma unroll
            for (int nf = 0; nf < 4; ++nf)
                b[nf] = *(const bf16x8*)(Bs + (wc * 64 + nf * 16 + fr) * BK + kk + 8 * fq);
#pragma unroll
            for (int mf = 0; mf < 4; ++mf)
#pragma unroll
                for (int nf = 0; nf < 4; ++nf)
                    acc[mf][nf] = __builtin_amdgcn_mfma_f32_16x16x32_bf16(
                        a[mf], b[nf], acc[mf][nf], 0, 0, 0);
        }
        __syncthreads();
    }

    // epilogue: C/D layout col=lane&15, row=4*(lane>>4)+i  [measured m89/m91]
#pragma unroll
    for (int nf = 0; nf < 4; ++nf) {
        const long col = n0 + wc * 64 + nf * 16 + fr;
        const float bias_v = BI[col];
#pragma unroll
        for (int mf = 0; mf < 4; ++mf) {
            const long rbase = m0 + wr * 64 + mf * 16 + 4 * fq;
#pragma unroll
            for (int i = 0; i < 4; ++i)
                Y[(rbase + i) * N + col] = acc[mf][nf][i] + bias_v;
        }
    }
}

// ---------------- fallback: round-2 fused kernel (verified) ----------------
__global__ void gptq_gemm_fallback(const float* __restrict__ X,
                                   const int* __restrict__ QW,
                                   const float* __restrict__ SC,
                                   const int* __restrict__ ZR,
                                   const float* __restrict__ BI,
                                   float* __restrict__ Y,
                                   int M, int N, int K, int G) {
    __shared__ __align__(16) short As[BM * PK];
    __shared__ __align__(16) short Bs[BN * PK];

    const int tid = threadIdx.x;
    const int nbm = M / BM;
    const int bid = blockIdx.x;
    const int cpx = gridDim.x >> 3;
    const int wgid = (bid & 7) * cpx + (bid >> 3);
    const int tm = wgid % nbm;
    const int tn = wgid / nbm;
    const long m0 = (long)tm * BM;
    const long n0 = (long)tn * BN;
    const int Kp = K >> 1;

    const int lane = tid & 63;
    const int wid = tid >> 6;
    const int wr = wid >> 1;
    const int wc = wid & 1;
    const int fr = lane & 15;
    const int fq = lane >> 4;

    int srow[4], sq[4];
#pragma unroll
    for (int c = 0; c < 4; ++c) {
        int w = tid + 256 * c;
        srow[c] = w >> 3;
        sq[c] = w & 7;
    }

    f32x4 acc[4][4] = {};
    const int NT = K / BK;

    for (int kt = 0; kt < NT; ++kt) {
        const int g = (kt * BK) / GS;
        f32x4 a0[4], a1[4];
        i32x4 b4[4];
        float sc_r[4], zr_r[4];
#pragma unroll
        for (int c = 0; c < 4; ++c) {
            const float* pa = X + (m0 + srow[c]) * K + kt * BK + 8 * sq[c];
            a0[c] = *(const f32x4*)pa;
            a1[c] = *(const f32x4*)(pa + 4);
            const int* pb = QW + (n0 + srow[c]) * Kp + kt * (BK / 2) + 4 * sq[c];
            b4[c] = *(const i32x4*)pb;
            sc_r[c] = SC[(n0 + srow[c]) * G + g];
            zr_r[c] = (float)ZR[(n0 + srow[c]) * G + g];
        }
        __syncthreads();
#pragma unroll
        for (int c = 0; c < 4; ++c) {
            bf16x8 av;
#pragma unroll
            for (int i = 0; i < 4; ++i) av[i] = f2bf(a0[c][i]);
#pragma unroll
            for (int i = 0; i < 4; ++i) av[4 + i] = f2bf(a1[c][i]);
            *(bf16x8*)(As + srow[c] * PK + 8 * sq[c]) = av;
            bf16x8 bv;
#pragma unroll
            for (int j = 0; j < 4; ++j) {
                int v = b4[c][j];
                bv[2 * j]     = f2bf(((float)(v & 15) - zr_r[c]) * sc_r[c]);
                bv[2 * j + 1] = f2bf(((float)((v >> 4) & 15) - zr_r[c]) * sc_r[c]);
            }
            *(bf16x8*)(Bs + srow[c] * PK + 8 * sq[c]) = bv;
        }
        __syncthreads();
#pragma unroll
        for (int kk = 0; kk < BK; kk += 32) {
            bf16x8 a[4], b[4];
#pragma unroll
            for (int mf = 0; mf < 4; ++mf)
                a[mf] = *(const bf16x8*)(As + (wr * 64 + mf * 16 + fr) * PK + kk + 8 * fq);
#pragma unroll
            for (int nf = 0; nf < 4; ++nf)
                b[nf] = *(const bf16x8*)(Bs + (wc * 64 + nf * 16 + fr) * PK + kk + 8 * fq);
#pragma unroll
            for (int mf = 0; mf < 4; ++mf)
#pragma unroll
                for (int nf = 0; nf < 4; ++nf)
                    acc[mf][nf] = __builtin_amdgcn_mfma_f32_16x16x32_bf16(
                        a[mf], b[nf], acc[mf][nf], 0, 0, 0);
        }
    }

#pragma unroll
    for (int nf = 0; nf < 4; ++nf) {
        const long col = n0 + wc * 64 + nf * 16 + fr;
        const float bias_v = BI[col];
#pragma unroll
        for (int mf = 0; mf < 4; ++mf) {
            const long rbase = m0 + wr * 64 + mf * 16 + 4 * fq;
#pragma unroll
            for (int i = 0; i < 4; ++i)
                Y[(rbase + i) * N + col] = acc[mf][nf][i] + bias_v;
        }
    }
}

extern "C" void kernel_launch(void* const* d_in, const int* in_sizes, int n_in,
                              void* d_out, int out_size, void* d_ws, size_t ws_size,
                              hipStream_t stream) {
    const float* X = (const float*)d_in[0];
    const int* QW = (const int*)d_in[1];
    const float* SC = (const float*)d_in[2];
    const int* ZR = (const int*)d_in[3];
    const float* BI = (const float*)d_in[4];
    float* Y = (float*)d_out;

    const int N = in_sizes[4];          // 4096
    const int G = in_sizes[2] / N;      // 32
    const int K = G * GS;               // 4096
    const int M = in_sizes[0] / K;      // 8192

    const size_t needW = (size_t)N * K * 2;
    const size_t needX = (size_t)M * K * 2;

    if (ws_size >= needW + needX) {
        short* Wb = (short*)d_ws;
        short* Xb = (short*)((char*)d_ws + needW);
        // prep
        const int dq_blocks = (N * (K / 32)) / 256;   // 2048
        hipLaunchKernelGGL(dequant_w_kernel, dim3(dq_blocks), dim3(256), 0, stream,
                           QW, SC, ZR, Wb, K, G);
        hipLaunchKernelGGL(cvt_x_kernel, dim3(2048), dim3(256), 0, stream,
                           X, Xb, (long)M * K);
        // gemm
        const int grid = (M / BM) * (N / BN);         // 2048, % 8 == 0
        hipLaunchKernelGGL(gemm_bf16_kernel, dim3(grid), dim3(256), 0, stream,
                           Xb, Wb, BI, Y, M, N, K);
    } else {
        const int grid = (M / BM) * (N / BN);
        hipLaunchKernelGGL(gptq_gemm_fallback, dim3(grid), dim3(256), 0, stream,
                           X, QW, SC, ZR, BI, Y, M, N, K, G);
    }
}

// Round 4
// 315.567 us; speedup vs baseline: 3.7293x; 1.2083x over previous
//
#include <hip/hip_runtime.h>
#include <hip/hip_bf16.h>

typedef __attribute__((ext_vector_type(4))) float f32x4;
typedef __attribute__((ext_vector_type(8))) short bf16x8;
typedef __attribute__((ext_vector_type(4))) int i32x4;

#define GS 128

#define GLOAD_LDS16(g, l)                                                        \
    __builtin_amdgcn_global_load_lds(                                            \
        (const __attribute__((address_space(1))) void*)(g),                      \
        (__attribute__((address_space(3))) void*)(l), 16, 0, 0)

__device__ __forceinline__ short f2bf(float f) {
    union { float f; unsigned u; } v; v.f = f;
    unsigned r = v.u + 0x7fffu + ((v.u >> 16) & 1u);
    return (short)(r >> 16);
}

__device__ __forceinline__ bf16x8 dq8(int q0, int q1, int q2, int q3, float s, float z) {
    bf16x8 r;
    int q[4] = {q0, q1, q2, q3};
#pragma unroll
    for (int j = 0; j < 4; ++j) {
        r[2 * j]     = f2bf(((float)(q[j] & 15) - z) * s);
        r[2 * j + 1] = f2bf(((float)((q[j] >> 4) & 15) - z) * s);
    }
    return r;
}

// ---------------- prep: dequant W -> bf16 (N x K row-major) ----------------
__global__ void dequant_w_kernel(const int* __restrict__ QW,
                                 const float* __restrict__ SC,
                                 const int* __restrict__ ZR,
                                 short* __restrict__ W, int K, int G) {
    const int cpr = K / 32;
    const int t = blockIdx.x * blockDim.x + threadIdx.x;
    const int o = t / cpr;
    const int c = t % cpr;
    const int g = (c * 32) / GS;
    const float s = SC[(long)o * G + g];
    const float z = (float)ZR[(long)o * G + g];
    const int* p = QW + (long)o * (K / 2) + c * 16;
    i32x4 v0 = *(const i32x4*)p;
    i32x4 v1 = *(const i32x4*)(p + 4);
    i32x4 v2 = *(const i32x4*)(p + 8);
    i32x4 v3 = *(const i32x4*)(p + 12);
    short* out = W + (long)o * K + c * 32;
    *(bf16x8*)(out)      = dq8(v0[0], v0[1], v0[2], v0[3], s, z);
    *(bf16x8*)(out + 8)  = dq8(v1[0], v1[1], v1[2], v1[3], s, z);
    *(bf16x8*)(out + 16) = dq8(v2[0], v2[1], v2[2], v2[3], s, z);
    *(bf16x8*)(out + 24) = dq8(v3[0], v3[1], v3[2], v3[3], s, z);
}

// ---------------- prep: convert X fp32 -> bf16 ----------------
__global__ void cvt_x_kernel(const float* __restrict__ X, short* __restrict__ Xb, long n) {
    long i = ((long)blockIdx.x * blockDim.x + threadIdx.x) * 8;
    const long stride = (long)gridDim.x * blockDim.x * 8;
    for (; i < n; i += stride) {
        f32x4 a = *(const f32x4*)(X + i);
        f32x4 b = *(const f32x4*)(X + i + 4);
        bf16x8 o;
#pragma unroll
        for (int j = 0; j < 4; ++j) { o[j] = f2bf(a[j]); o[4 + j] = f2bf(b[j]); }
        *(bf16x8*)(Xb + i) = o;
    }
}

// ---------------- main: 256x256 8-phase bf16 GEMM (T2+T3+T4+T5) ----------------
// 512 threads = 8 waves (2M x 4N). BK=64. LDS: 2 bufs x {A 32KB | B 32KB} = 128KB.
// Swizzle: st_16x32 (byte ^= ((byte>>9)&1)<<5) via inverse-swz global source +
// swz read (linear gload_lds dest). Counted vmcnt: boundary vmcnt(2), mid vmcnt(4).
__global__ __launch_bounds__(512, 2)
void gemm256_kernel(const short* __restrict__ A,   // M x K bf16
                    const short* __restrict__ B,   // N x K bf16
                    const float* __restrict__ BI,
                    float* __restrict__ Y,
                    int M, int N, int K) {
    extern __shared__ char smem[];   // 131072 bytes

    const int tid = threadIdx.x;
    const int lane = tid & 63;
    const int wid = tid >> 6;
    const int wr = wid >> 2;     // 0..1 (M)
    const int wc = wid & 3;      // 0..3 (N)
    const int fr = lane & 15;
    const int fq = lane >> 4;

    const int nbm = M / 256;
    const int bid = blockIdx.x;
    const int cpx = gridDim.x >> 3;
    const int wgid = (bid & 7) * cpx + (bid >> 3);   // bijective XCD swizzle (grid%8==0)
    const int tm = wgid % nbm;
    const int tn = wgid / nbm;
    const long m0 = (long)tm * 256;
    const long n0 = (long)tn * 256;

    // staging: issue (region i) covers rows [i*64, i*64+64); this wave's 8 rows.
    // gload_lds dest is linear (base + lane*16); source chunk pre-swizzled so the
    // LDS holds the st_16x32 layout.
    const int srow = wid * 8 + (lane >> 3);                     // row within region
    const int schunk = (lane & 7) ^ (((lane >> 5) & 1) << 1);   // inverse-swz chunk
    const short* gA = A + (m0 + srow) * (long)K + schunk * 8;
    const short* gB = B + (n0 + srow) * (long)K + schunk * 8;

    auto stageA = [&](int c, int i, int kt) {
        GLOAD_LDS16(gA + (long)i * 64 * K + kt * 64,
                    smem + c * 65536 + i * 8192 + wid * 1024);
    };
    auto stageB = [&](int c, int i, int kt) {
        GLOAD_LDS16(gB + (long)i * 64 * K + kt * 64,
                    smem + c * 65536 + 32768 + i * 8192 + wid * 1024);
    };

    const int rswz = ((fr >> 2) & 1) << 1;   // swz on read: chunk ^= bit

    f32x4 acc[8][4] = {};
    bf16x8 bfr[4][2];   // [nf][ks] — live for a whole K-tile
    bf16x8 afr[2][2];   // [ml][ks] — per phase

    const int NT = K / 64;

    // prologue: stage tile 0 in steady-state order, drain once, barrier
    stageB(0, 0, 0); stageB(0, 1, 0); stageB(0, 2, 0); stageB(0, 3, 0);
    stageA(0, 0, 0); stageA(0, 2, 0); stageA(0, 1, 0); stageA(0, 3, 0);
    asm volatile("s_waitcnt vmcnt(0)" ::: "memory");
    __builtin_amdgcn_s_barrier();

    for (int t = 0; t < NT - 1; ++t) {
        const int cur = t & 1;
        const char* sA = smem + cur * 65536;
        const char* sB = sA + 32768;
        const int nxt = cur ^ 1;
#pragma unroll
        for (int q = 0; q < 4; ++q) {
            // ds-reads for THIS phase's MFMA (A-subtile; +B whole tile at q==0)
#pragma unroll
            for (int ml = 0; ml < 2; ++ml)
#pragma unroll
                for (int ks = 0; ks < 2; ++ks) {
                    int row = wr * 128 + (2 * q + ml) * 16 + fr;
                    afr[ml][ks] = *(const bf16x8*)(sA + row * 128 + ((fq + 4 * ks) ^ rswz) * 16);
                }
            if (q == 0) {
#pragma unroll
                for (int nf = 0; nf < 4; ++nf)
#pragma unroll
                    for (int ks = 0; ks < 2; ++ks) {
                        int row = wc * 64 + nf * 16 + fr;
                        bfr[nf][ks] = *(const bf16x8*)(sB + row * 128 + ((fq + 4 * ks) ^ rswz) * 16);
                    }
            }
            // stage 2 issues for tile t+1 (order: B0,B1 | B2,B3 | A0,A2 | A1,A3)
            if (q == 0)      { stageB(nxt, 0, t + 1); stageB(nxt, 1, t + 1); }
            else if (q == 1) { stageB(nxt, 2, t + 1); stageB(nxt, 3, t + 1); }
            else if (q == 2) { stageA(nxt, 0, t + 1); stageA(nxt, 2, t + 1); }
            else             { stageA(nxt, 1, t + 1); stageA(nxt, 3, t + 1); }

            __builtin_amdgcn_s_barrier();
            __builtin_amdgcn_s_setprio(1);
#pragma unroll
            for (int ml = 0; ml < 2; ++ml)
#pragma unroll
                for (int nf = 0; nf < 4; ++nf)
#pragma unroll
                    for (int ks = 0; ks < 2; ++ks)
                        acc[2 * q + ml][nf] = __builtin_amdgcn_mfma_f32_16x16x32_bf16(
                            afr[ml][ks], bfr[nf][ks], acc[2 * q + ml][nf], 0, 0, 0);
            __builtin_amdgcn_s_setprio(0);
            // counted waits: A1,A3 of tile t+1 must land before its phase 2;
            // B*,A0,A2 before its phase 0. Never vmcnt(0) in the main loop.
            if (q == 1) asm volatile("s_waitcnt vmcnt(4)" ::: "memory");
            if (q == 3) asm volatile("s_waitcnt vmcnt(2)" ::: "memory");
            __builtin_amdgcn_s_barrier();
        }
    }

    // epilogue: last K-tile, no staging
    {
        const int cur = (NT - 1) & 1;
        const char* sA = smem + cur * 65536;
        const char* sB = sA + 32768;
#pragma unroll
        for (int q = 0; q < 4; ++q) {
#pragma unroll
            for (int ml = 0; ml < 2; ++ml)
#pragma unroll
                for (int ks = 0; ks < 2; ++ks) {
                    int row = wr * 128 + (2 * q + ml) * 16 + fr;
                    afr[ml][ks] = *(const bf16x8*)(sA + row * 128 + ((fq + 4 * ks) ^ rswz) * 16);
                }
            if (q == 0) {
#pragma unroll
                for (int nf = 0; nf < 4; ++nf)
#pragma unroll
                    for (int ks = 0; ks < 2; ++ks) {
                        int row = wc * 64 + nf * 16 + fr;
                        bfr[nf][ks] = *(const bf16x8*)(sB + row * 128 + ((fq + 4 * ks) ^ rswz) * 16);
                    }
            }
            __builtin_amdgcn_s_barrier();
            __builtin_amdgcn_s_setprio(1);
#pragma unroll
            for (int ml = 0; ml < 2; ++ml)
#pragma unroll
                for (int nf = 0; nf < 4; ++nf)
#pragma unroll
                    for (int ks = 0; ks < 2; ++ks)
                        acc[2 * q + ml][nf] = __builtin_amdgcn_mfma_f32_16x16x32_bf16(
                            afr[ml][ks], bfr[nf][ks], acc[2 * q + ml][nf], 0, 0, 0);
            __builtin_amdgcn_s_setprio(0);
            if (q == 1) asm volatile("s_waitcnt vmcnt(0)" ::: "memory");
            __builtin_amdgcn_s_barrier();
        }
    }

    // C-write: C/D layout col=lane&15, row=4*(lane>>4)+i  [measured m89/m91]
#pragma unroll
    for (int nf = 0; nf < 4; ++nf) {
        const long col = n0 + wc * 64 + nf * 16 + fr;
        const float bv = BI[col];
#pragma unroll
        for (int m = 0; m < 8; ++m) {
            const long rbase = m0 + wr * 128 + m * 16 + 4 * fq;
#pragma unroll
            for (int i = 0; i < 4; ++i)
                Y[(rbase + i) * N + col] = acc[m][nf][i] + bv;
        }
    }
}

// ---------------- fallback: fused kernel (verified round 2) ----------------
#define BM 128
#define BN 128
#define BK 64
#define PK 72

__global__ void gptq_gemm_fallback(const float* __restrict__ X,
                                   const int* __restrict__ QW,
                                   const float* __restrict__ SC,
                                   const int* __restrict__ ZR,
                                   const float* __restrict__ BI,
                                   float* __restrict__ Y,
                                   int M, int N, int K, int G) {
    __shared__ __align__(16) short As[BM * PK];
    __shared__ __align__(16) short Bs[BN * PK];

    const int tid = threadIdx.x;
    const int nbm = M / BM;
    const int bid = blockIdx.x;
    const int cpx = gridDim.x >> 3;
    const int wgid = (bid & 7) * cpx + (bid >> 3);
    const int tm = wgid % nbm;
    const int tn = wgid / nbm;
    const long m0 = (long)tm * BM;
    const long n0 = (long)tn * BN;
    const int Kp = K >> 1;

    const int lane = tid & 63;
    const int wid = tid >> 6;
    const int wr = wid >> 1;
    const int wc = wid & 1;
    const int fr = lane & 15;
    const int fq = lane >> 4;

    int srow[4], sq[4];
#pragma unroll
    for (int c = 0; c < 4; ++c) {
        int w = tid + 256 * c;
        srow[c] = w >> 3;
        sq[c] = w & 7;
    }

    f32x4 acc[4][4] = {};
    const int NT = K / BK;

    for (int kt = 0; kt < NT; ++kt) {
        const int g = (kt * BK) / GS;
        f32x4 a0[4], a1[4];
        i32x4 b4[4];
        float sc_r[4], zr_r[4];
#pragma unroll
        for (int c = 0; c < 4; ++c) {
            const float* pa = X + (m0 + srow[c]) * K + kt * BK + 8 * sq[c];
            a0[c] = *(const f32x4*)pa;
            a1[c] = *(const f32x4*)(pa + 4);
            const int* pb = QW + (n0 + srow[c]) * Kp + kt * (BK / 2) + 4 * sq[c];
            b4[c] = *(const i32x4*)pb;
            sc_r[c] = SC[(n0 + srow[c]) * G + g];
            zr_r[c] = (float)ZR[(n0 + srow[c]) * G + g];
        }
        __syncthreads();
#pragma unroll
        for (int c = 0; c < 4; ++c) {
            bf16x8 av;
#pragma unroll
            for (int i = 0; i < 4; ++i) av[i] = f2bf(a0[c][i]);
#pragma unroll
            for (int i = 0; i < 4; ++i) av[4 + i] = f2bf(a1[c][i]);
            *(bf16x8*)(As + srow[c] * PK + 8 * sq[c]) = av;
            bf16x8 bv;
#pragma unroll
            for (int j = 0; j < 4; ++j) {
                int v = b4[c][j];
                bv[2 * j]     = f2bf(((float)(v & 15) - zr_r[c]) * sc_r[c]);
                bv[2 * j + 1] = f2bf(((float)((v >> 4) & 15) - zr_r[c]) * sc_r[c]);
            }
            *(bf16x8*)(Bs + srow[c] * PK + 8 * sq[c]) = bv;
        }
        __syncthreads();
#pragma unroll
        for (int kk = 0; kk < BK; kk += 32) {
            bf16x8 a[4], b[4];
#pragma unroll
            for (int mf = 0; mf < 4; ++mf)
                a[mf] = *(const bf16x8*)(As + (wr * 64 + mf * 16 + fr) * PK + kk + 8 * fq);
#pragma unroll
            for (int nf = 0; nf < 4; ++nf)
                b[nf] = *(const bf16x8*)(Bs + (wc * 64 + nf * 16 + fr) * PK + kk + 8 * fq);
#pragma unroll
            for (int mf = 0; mf < 4; ++mf)
#pragma unroll
                for (int nf = 0; nf < 4; ++nf)
                    acc[mf][nf] = __builtin_amdgcn_mfma_f32_16x16x32_bf16(
                        a[mf], b[nf], acc[mf][nf], 0, 0, 0);
        }
    }

#pragma unroll
    for (int nf = 0; nf < 4; ++nf) {
        const long col = n0 + wc * 64 + nf * 16 + fr;
        const float bias_v = BI[col];
#pragma unroll
        for (int mf = 0; mf < 4; ++mf) {
            const long rbase = m0 + wr * 64 + mf * 16 + 4 * fq;
#pragma unroll
            for (int i = 0; i < 4; ++i)
                Y[(rbase + i) * N + col] = acc[mf][nf][i] + bias_v;
        }
    }
}

extern "C" void kernel_launch(void* const* d_in, const int* in_sizes, int n_in,
                              void* d_out, int out_size, void* d_ws, size_t ws_size,
                              hipStream_t stream) {
    const float* X = (const float*)d_in[0];
    const int* QW = (const int*)d_in[1];
    const float* SC = (const float*)d_in[2];
    const int* ZR = (const int*)d_in[3];
    const float* BI = (const float*)d_in[4];
    float* Y = (float*)d_out;

    const int N = in_sizes[4];          // 4096
    const int G = in_sizes[2] / N;      // 32
    const int K = G * GS;               // 4096
    const int M = in_sizes[0] / K;      // 8192

    const size_t needW = (size_t)N * K * 2;
    const size_t needX = (size_t)M * K * 2;

    if (ws_size >= needW + needX) {
        short* Wb = (short*)d_ws;
        short* Xb = (short*)((char*)d_ws + needW);
        const int dq_blocks = (N * (K / 32)) / 256;
        hipLaunchKernelGGL(dequant_w_kernel, dim3(dq_blocks), dim3(256), 0, stream,
                           QW, SC, ZR, Wb, K, G);
        hipLaunchKernelGGL(cvt_x_kernel, dim3(2048), dim3(256), 0, stream,
                           X, Xb, (long)M * K);
        (void)hipFuncSetAttribute((const void*)gemm256_kernel,
                                  hipFuncAttributeMaxDynamicSharedMemorySize, 131072);
        const int grid = (M / 256) * (N / 256);   // 512, % 8 == 0
        hipLaunchKernelGGL(gemm256_kernel, dim3(grid), dim3(512), 131072, stream,
                           Xb, Wb, BI, Y, M, N, K);
    } else {
        const int grid = (M / BM) * (N / BN);
        hipLaunchKernelGGL(gptq_gemm_fallback, dim3(grid), dim3(256), 0, stream,
                           X, QW, SC, ZR, BI, Y, M, N, K, G);
    }
}

// Round 5
// 294.218 us; speedup vs baseline: 3.9999x; 1.0726x over previous
//
#include <hip/hip_runtime.h>
#include <hip/hip_bf16.h>

typedef __attribute__((ext_vector_type(4))) float f32x4;
typedef __attribute__((ext_vector_type(8))) short bf16x8;
typedef __attribute__((ext_vector_type(4))) int i32x4;

#define GS 128

#define GLOAD_LDS16(g, l)                                                        \
    __builtin_amdgcn_global_load_lds(                                            \
        (const __attribute__((address_space(1))) void*)(g),                      \
        (__attribute__((address_space(3))) void*)(l), 16, 0, 0)

__device__ __forceinline__ short f2bf(float f) {
    union { float f; unsigned u; } v; v.f = f;
    unsigned r = v.u + 0x7fffu + ((v.u >> 16) & 1u);
    return (short)(r >> 16);
}

__device__ __forceinline__ bf16x8 dq8(int q0, int q1, int q2, int q3, float s, float z) {
    bf16x8 r;
    int q[4] = {q0, q1, q2, q3};
#pragma unroll
    for (int j = 0; j < 4; ++j) {
        r[2 * j]     = f2bf(((float)(q[j] & 15) - z) * s);
        r[2 * j + 1] = f2bf(((float)((q[j] >> 4) & 15) - z) * s);
    }
    return r;
}

// ---------------- prep: dequant W -> bf16 (N x K row-major) ----------------
__global__ void dequant_w_kernel(const int* __restrict__ QW,
                                 const float* __restrict__ SC,
                                 const int* __restrict__ ZR,
                                 short* __restrict__ W, int K, int G) {
    const int cpr = K / 32;
    const int t = blockIdx.x * blockDim.x + threadIdx.x;
    const int o = t / cpr;
    const int c = t % cpr;
    const int g = (c * 32) / GS;
    const float s = SC[(long)o * G + g];
    const float z = (float)ZR[(long)o * G + g];
    const int* p = QW + (long)o * (K / 2) + c * 16;
    i32x4 v0 = *(const i32x4*)p;
    i32x4 v1 = *(const i32x4*)(p + 4);
    i32x4 v2 = *(const i32x4*)(p + 8);
    i32x4 v3 = *(const i32x4*)(p + 12);
    short* out = W + (long)o * K + c * 32;
    *(bf16x8*)(out)      = dq8(v0[0], v0[1], v0[2], v0[3], s, z);
    *(bf16x8*)(out + 8)  = dq8(v1[0], v1[1], v1[2], v1[3], s, z);
    *(bf16x8*)(out + 16) = dq8(v2[0], v2[1], v2[2], v2[3], s, z);
    *(bf16x8*)(out + 24) = dq8(v3[0], v3[1], v3[2], v3[3], s, z);
}

// ---------------- prep: convert X fp32 -> bf16 ----------------
__global__ void cvt_x_kernel(const float* __restrict__ X, short* __restrict__ Xb, long n) {
    long i = ((long)blockIdx.x * blockDim.x + threadIdx.x) * 8;
    const long stride = (long)gridDim.x * blockDim.x * 8;
    for (; i < n; i += stride) {
        f32x4 a = *(const f32x4*)(X + i);
        f32x4 b = *(const f32x4*)(X + i + 4);
        bf16x8 o;
#pragma unroll
        for (int j = 0; j < 4; ++j) { o[j] = f2bf(a[j]); o[4 + j] = f2bf(b[j]); }
        *(bf16x8*)(Xb + i) = o;
    }
}

// ---------------- main: 256x256 8-phase bf16 GEMM (T2+T3+T4+T5) ----------------
// 512 threads = 8 waves (2M x 4N). BK=64. LDS: 2 bufs x {A 32KB | B 32KB} = 128KB.
// T2 swizzle: full 3-bit chunk ^= (row&7) involution (G4-measured fix for 128B
// row stride), applied as inverse-swz global SOURCE (linear gload_lds dest) +
// swz on READ. Counted vmcnt: boundary vmcnt(2), mid vmcnt(4); never 0 in loop.
__global__ __launch_bounds__(512, 2)
void gemm256_kernel(const short* __restrict__ A,   // M x K bf16
                    const short* __restrict__ B,   // N x K bf16
                    const float* __restrict__ BI,
                    float* __restrict__ Y,
                    int M, int N, int K) {
    extern __shared__ char smem[];   // 131072 bytes

    const int tid = threadIdx.x;
    const int lane = tid & 63;
    const int wid = tid >> 6;
    const int wr = wid >> 2;     // 0..1 (M)
    const int wc = wid & 3;      // 0..3 (N)
    const int fr = lane & 15;
    const int fq = lane >> 4;

    const int nbn = N / 256;
    const int bid = blockIdx.x;
    const int cpx = gridDim.x >> 3;
    const int wgid = (bid & 7) * cpx + (bid >> 3);   // bijective XCD swizzle (grid%8==0)
    const int tm = wgid / nbn;   // consecutive wgids share the X-panel (L2-resident);
    const int tn = wgid % nbn;   // W panels are chip-shared via L3
    const long m0 = (long)tm * 256;
    const long n0 = (long)tn * 256;

    // staging: issue (region i) covers rows [i*64, i*64+64); this wave's 8 rows.
    // LDS dest linear; source chunk = (lane&7) ^ (row&7), row&7 = lane>>3, so the
    // LDS ends up holding LDS[row][c] = global[row][c ^ (row&7)].
    const int srow = wid * 8 + (lane >> 3);             // row within region
    const int schunk = (lane & 7) ^ (lane >> 3);        // inverse-swz source chunk
    const short* gA = A + (m0 + srow) * (long)K + schunk * 8;
    const short* gB = B + (n0 + srow) * (long)K + schunk * 8;

    auto stageA = [&](int c, int i, int kt) {
        GLOAD_LDS16(gA + (long)i * 64 * K + kt * 64,
                    smem + c * 65536 + i * 8192 + wid * 1024);
    };
    auto stageB = [&](int c, int i, int kt) {
        GLOAD_LDS16(gB + (long)i * 64 * K + kt * 64,
                    smem + c * 65536 + 32768 + i * 8192 + wid * 1024);
    };

    const int rswz = fr & 7;   // read-side: chunk ^= (row&7), row&7 == fr&7 always

    f32x4 acc[8][4] = {};
    bf16x8 bfr[4][2];   // [nf][ks] — live for a whole K-tile
    bf16x8 afr[2][2];   // [ml][ks] — per phase

    const int NT = K / 64;

    // prologue: stage tile 0 in steady-state order, drain once, barrier
    stageB(0, 0, 0); stageB(0, 1, 0); stageB(0, 2, 0); stageB(0, 3, 0);
    stageA(0, 0, 0); stageA(0, 2, 0); stageA(0, 1, 0); stageA(0, 3, 0);
    asm volatile("s_waitcnt vmcnt(0)" ::: "memory");
    __builtin_amdgcn_s_barrier();

    for (int t = 0; t < NT - 1; ++t) {
        const int cur = t & 1;
        const char* sA = smem + cur * 65536;
        const char* sB = sA + 32768;
        const int nxt = cur ^ 1;
#pragma unroll
        for (int q = 0; q < 4; ++q) {
            // ds-reads for THIS phase's MFMA (A-subtile; +B whole tile at q==0)
#pragma unroll
            for (int ml = 0; ml < 2; ++ml)
#pragma unroll
                for (int ks = 0; ks < 2; ++ks) {
                    int row = wr * 128 + (2 * q + ml) * 16 + fr;
                    afr[ml][ks] = *(const bf16x8*)(sA + row * 128 + ((fq + 4 * ks) ^ rswz) * 16);
                }
            if (q == 0) {
#pragma unroll
                for (int nf = 0; nf < 4; ++nf)
#pragma unroll
                    for (int ks = 0; ks < 2; ++ks) {
                        int row = wc * 64 + nf * 16 + fr;
                        bfr[nf][ks] = *(const bf16x8*)(sB + row * 128 + ((fq + 4 * ks) ^ rswz) * 16);
                    }
            }
            // stage 2 issues for tile t+1 (order: B0,B1 | B2,B3 | A0,A2 | A1,A3)
            if (q == 0)      { stageB(nxt, 0, t + 1); stageB(nxt, 1, t + 1); }
            else if (q == 1) { stageB(nxt, 2, t + 1); stageB(nxt, 3, t + 1); }
            else if (q == 2) { stageA(nxt, 0, t + 1); stageA(nxt, 2, t + 1); }
            else             { stageA(nxt, 1, t + 1); stageA(nxt, 3, t + 1); }

            if (q == 0) asm volatile("s_waitcnt lgkmcnt(8)" ::: "memory");  // partial drain (12 reads issued)
            __builtin_amdgcn_s_barrier();
            __builtin_amdgcn_s_setprio(1);
#pragma unroll
            for (int ml = 0; ml < 2; ++ml)
#pragma unroll
                for (int nf = 0; nf < 4; ++nf)
#pragma unroll
                    for (int ks = 0; ks < 2; ++ks)
                        acc[2 * q + ml][nf] = __builtin_amdgcn_mfma_f32_16x16x32_bf16(
                            afr[ml][ks], bfr[nf][ks], acc[2 * q + ml][nf], 0, 0, 0);
            __builtin_amdgcn_s_setprio(0);
            // counted waits: A1,A3 of tile t+1 must land before its phase 2;
            // B*,A0,A2 before its phase 0. Never vmcnt(0) in the main loop.
            if (q == 1) asm volatile("s_waitcnt vmcnt(4)" ::: "memory");
            if (q == 3) asm volatile("s_waitcnt vmcnt(2)" ::: "memory");
            __builtin_amdgcn_s_barrier();
        }
    }

    // epilogue: last K-tile, no staging
    {
        const int cur = (NT - 1) & 1;
        const char* sA = smem + cur * 65536;
        const char* sB = sA + 32768;
#pragma unroll
        for (int q = 0; q < 4; ++q) {
#pragma unroll
            for (int ml = 0; ml < 2; ++ml)
#pragma unroll
                for (int ks = 0; ks < 2; ++ks) {
                    int row = wr * 128 + (2 * q + ml) * 16 + fr;
                    afr[ml][ks] = *(const bf16x8*)(sA + row * 128 + ((fq + 4 * ks) ^ rswz) * 16);
                }
            if (q == 0) {
#pragma unroll
                for (int nf = 0; nf < 4; ++nf)
#pragma unroll
                    for (int ks = 0; ks < 2; ++ks) {
                        int row = wc * 64 + nf * 16 + fr;
                        bfr[nf][ks] = *(const bf16x8*)(sB + row * 128 + ((fq + 4 * ks) ^ rswz) * 16);
                    }
            }
            __builtin_amdgcn_s_barrier();
            __builtin_amdgcn_s_setprio(1);
#pragma unroll
            for (int ml = 0; ml < 2; ++ml)
#pragma unroll
                for (int nf = 0; nf < 4; ++nf)
#pragma unroll
                    for (int ks = 0; ks < 2; ++ks)
                        acc[2 * q + ml][nf] = __builtin_amdgcn_mfma_f32_16x16x32_bf16(
                            afr[ml][ks], bfr[nf][ks], acc[2 * q + ml][nf], 0, 0, 0);
            __builtin_amdgcn_s_setprio(0);
            if (q == 1) asm volatile("s_waitcnt vmcnt(0)" ::: "memory");
            __builtin_amdgcn_s_barrier();
        }
    }

    // C-write: C/D layout col=lane&15, row=4*(lane>>4)+i  [measured m89/m91]
#pragma unroll
    for (int nf = 0; nf < 4; ++nf) {
        const long col = n0 + wc * 64 + nf * 16 + fr;
        const float bv = BI[col];
#pragma unroll
        for (int m = 0; m < 8; ++m) {
            const long rbase = m0 + wr * 128 + m * 16 + 4 * fq;
#pragma unroll
            for (int i = 0; i < 4; ++i)
                Y[(rbase + i) * N + col] = acc[m][nf][i] + bv;
        }
    }
}

// ---------------- fallback: fused kernel (verified round 2) ----------------
#define BM 128
#define BN 128
#define BK 64
#define PK 72

__global__ void gptq_gemm_fallback(const float* __restrict__ X,
                                   const int* __restrict__ QW,
                                   const float* __restrict__ SC,
                                   const int* __restrict__ ZR,
                                   const float* __restrict__ BI,
                                   float* __restrict__ Y,
                                   int M, int N, int K, int G) {
    __shared__ __align__(16) short As[BM * PK];
    __shared__ __align__(16) short Bs[BN * PK];

    const int tid = threadIdx.x;
    const int nbm = M / BM;
    const int bid = blockIdx.x;
    const int cpx = gridDim.x >> 3;
    const int wgid = (bid & 7) * cpx + (bid >> 3);
    const int tm = wgid % nbm;
    const int tn = wgid / nbm;
    const long m0 = (long)tm * BM;
    const long n0 = (long)tn * BN;
    const int Kp = K >> 1;

    const int lane = tid & 63;
    const int wid = tid >> 6;
    const int wr = wid >> 1;
    const int wc = wid & 1;
    const int fr = lane & 15;
    const int fq = lane >> 4;

    int srow[4], sq[4];
#pragma unroll
    for (int c = 0; c < 4; ++c) {
        int w = tid + 256 * c;
        srow[c] = w >> 3;
        sq[c] = w & 7;
    }

    f32x4 acc[4][4] = {};
    const int NT = K / BK;

    for (int kt = 0; kt < NT; ++kt) {
        const int g = (kt * BK) / GS;
        f32x4 a0[4], a1[4];
        i32x4 b4[4];
        float sc_r[4], zr_r[4];
#pragma unroll
        for (int c = 0; c < 4; ++c) {
            const float* pa = X + (m0 + srow[c]) * K + kt * BK + 8 * sq[c];
            a0[c] = *(const f32x4*)pa;
            a1[c] = *(const f32x4*)(pa + 4);
            const int* pb = QW + (n0 + srow[c]) * Kp + kt * (BK / 2) + 4 * sq[c];
            b4[c] = *(const i32x4*)pb;
            sc_r[c] = SC[(n0 + srow[c]) * G + g];
            zr_r[c] = (float)ZR[(n0 + srow[c]) * G + g];
        }
        __syncthreads();
#pragma unroll
        for (int c = 0; c < 4; ++c) {
            bf16x8 av;
#pragma unroll
            for (int i = 0; i < 4; ++i) av[i] = f2bf(a0[c][i]);
#pragma unroll
            for (int i = 0; i < 4; ++i) av[4 + i] = f2bf(a1[c][i]);
            *(bf16x8*)(As + srow[c] * PK + 8 * sq[c]) = av;
            bf16x8 bv;
#pragma unroll
            for (int j = 0; j < 4; ++j) {
                int v = b4[c][j];
                bv[2 * j]     = f2bf(((float)(v & 15) - zr_r[c]) * sc_r[c]);
                bv[2 * j + 1] = f2bf(((float)((v >> 4) & 15) - zr_r[c]) * sc_r[c]);
            }
            *(bf16x8*)(Bs + srow[c] * PK + 8 * sq[c]) = bv;
        }
        __syncthreads();
#pragma unroll
        for (int kk = 0; kk < BK; kk += 32) {
            bf16x8 a[4], b[4];
#pragma unroll
            for (int mf = 0; mf < 4; ++mf)
                a[mf] = *(const bf16x8*)(As + (wr * 64 + mf * 16 + fr) * PK + kk + 8 * fq);
#pragma unroll
            for (int nf = 0; nf < 4; ++nf)
                b[nf] = *(const bf16x8*)(Bs + (wc * 64 + nf * 16 + fr) * PK + kk + 8 * fq);
#pragma unroll
            for (int mf = 0; mf < 4; ++mf)
#pragma unroll
                for (int nf = 0; nf < 4; ++nf)
                    acc[mf][nf] = __builtin_amdgcn_mfma_f32_16x16x32_bf16(
                        a[mf], b[nf], acc[mf][nf], 0, 0, 0);
        }
    }

#pragma unroll
    for (int nf = 0; nf < 4; ++nf) {
        const long col = n0 + wc * 64 + nf * 16 + fr;
        const float bias_v = BI[col];
#pragma unroll
        for (int mf = 0; mf < 4; ++mf) {
            const long rbase = m0 + wr * 64 + mf * 16 + 4 * fq;
#pragma unroll
            for (int i = 0; i < 4; ++i)
                Y[(rbase + i) * N + col] = acc[mf][nf][i] + bias_v;
        }
    }
}

extern "C" void kernel_launch(void* const* d_in, const int* in_sizes, int n_in,
                              void* d_out, int out_size, void* d_ws, size_t ws_size,
                              hipStream_t stream) {
    const float* X = (const float*)d_in[0];
    const int* QW = (const int*)d_in[1];
    const float* SC = (const float*)d_in[2];
    const int* ZR = (const int*)d_in[3];
    const float* BI = (const float*)d_in[4];
    float* Y = (float*)d_out;

    const int N = in_sizes[4];          // 4096
    const int G = in_sizes[2] / N;      // 32
    const int K = G * GS;               // 4096
    const int M = in_sizes[0] / K;      // 8192

    const size_t needW = (size_t)N * K * 2;
    const size_t needX = (size_t)M * K * 2;

    if (ws_size >= needW + needX) {
        short* Wb = (short*)d_ws;
        short* Xb = (short*)((char*)d_ws + needW);
        const int dq_blocks = (N * (K / 32)) / 256;
        hipLaunchKernelGGL(dequant_w_kernel, dim3(dq_blocks), dim3(256), 0, stream,
                           QW, SC, ZR, Wb, K, G);
        hipLaunchKernelGGL(cvt_x_kernel, dim3(2048), dim3(256), 0, stream,
                           X, Xb, (long)M * K);
        (void)hipFuncSetAttribute((const void*)gemm256_kernel,
                                  hipFuncAttributeMaxDynamicSharedMemorySize, 131072);
        const int grid = (M / 256) * (N / 256);   // 512, % 8 == 0
        hipLaunchKernelGGL(gemm256_kernel, dim3(grid), dim3(512), 131072, stream,
                           Xb, Wb, BI, Y, M, N, K);
    } else {
        const int grid = (M / BM) * (N / BN);
        hipLaunchKernelGGL(gptq_gemm_fallback, dim3(grid), dim3(256), 0, stream,
                           X, QW, SC, ZR, BI, Y, M, N, K, G);
    }
}

// Round 6
// 241.606 us; speedup vs baseline: 4.8709x; 1.2178x over previous
//
#include <hip/hip_runtime.h>
#include <hip/hip_bf16.h>

typedef __attribute__((ext_vector_type(4))) float f32x4;
typedef __attribute__((ext_vector_type(8))) short bf16x8;
typedef __attribute__((ext_vector_type(4))) int i32x4;

#define GS 128

#define GLOAD_LDS16(g, l)                                                        \
    __builtin_amdgcn_global_load_lds(                                            \
        (const __attribute__((address_space(1))) void*)(g),                      \
        (__attribute__((address_space(3))) void*)(l), 16, 0, 0)

__device__ __forceinline__ short f2bf(float f) {
    union { float f; unsigned u; } v; v.f = f;
    unsigned r = v.u + 0x7fffu + ((v.u >> 16) & 1u);
    return (short)(r >> 16);
}

// ---------------- prep: W -> int8 (q - z), exact ----------------
__global__ void quant_w_kernel(const int* __restrict__ QW,
                               const int* __restrict__ ZR,
                               signed char* __restrict__ W8, int K, int G) {
    const int cpr = K / 32;                     // 32-k chunks per row
    const int t = blockIdx.x * blockDim.x + threadIdx.x;
    const int o = t / cpr;
    const int c = t % cpr;
    const int g = (c * 32) / GS;
    const int z = ZR[(long)o * G + g];
    const int* p = QW + (long)o * (K / 2) + c * 16;
    int out[8];
#pragma unroll
    for (int j = 0; j < 8; ++j) {
        int v0 = p[2 * j];
        int v1 = p[2 * j + 1];
        int b0 = ((v0 & 15) - z) & 255;
        int b1 = (((v0 >> 4) & 15) - z) & 255;
        int b2 = ((v1 & 15) - z) & 255;
        int b3 = (((v1 >> 4) & 15) - z) & 255;
        out[j] = b0 | (b1 << 8) | (b2 << 16) | (b3 << 24);
    }
    i32x4* dst = (i32x4*)(W8 + (long)o * K + c * 32);
    dst[0] = *(i32x4*)&out[0];
    dst[1] = *(i32x4*)&out[4];
}

// ---------------- prep: transpose scales -> ST[g][o] ----------------
__global__ void sct_kernel(const float* __restrict__ SC, float* __restrict__ ST,
                           int N, int G) {
    int t = blockIdx.x * blockDim.x + threadIdx.x;   // N*G total
    int g = t / N;
    int o = t % N;                                   // coalesced write
    ST[(long)g * N + o] = SC[(long)o * G + g];
}

// ---------------- prep: per-row dynamic int8 quant of X ----------------
__global__ void quant_x_kernel(const float* __restrict__ X,
                               signed char* __restrict__ Xq,
                               float* __restrict__ XS, int K) {
    const int row = blockIdx.x;
    const int tid = threadIdx.x;                     // 256, each 16 floats
    const int lane = tid & 63;
    const int wid = tid >> 6;
    const float* px = X + (long)row * K + tid * 16;
    f32x4 v[4];
#pragma unroll
    for (int j = 0; j < 4; ++j) v[j] = *(const f32x4*)(px + j * 4);
    float am = 0.f;
#pragma unroll
    for (int j = 0; j < 4; ++j)
#pragma unroll
        for (int i = 0; i < 4; ++i) am = fmaxf(am, fabsf(v[j][i]));
#pragma unroll
    for (int off = 32; off >= 1; off >>= 1) am = fmaxf(am, __shfl_xor(am, off));
    __shared__ float red[4];
    if (lane == 0) red[wid] = am;
    __syncthreads();
    float amax = fmaxf(fmaxf(red[0], red[1]), fmaxf(red[2], red[3]));
    amax = fmaxf(amax, 1e-30f);
    const float qs = 127.0f / amax;
    int out[4];
#pragma unroll
    for (int j = 0; j < 4; ++j) {
        int b0 = ((int)rintf(v[j][0] * qs)) & 255;
        int b1 = ((int)rintf(v[j][1] * qs)) & 255;
        int b2 = ((int)rintf(v[j][2] * qs)) & 255;
        int b3 = ((int)rintf(v[j][3] * qs)) & 255;
        out[j] = b0 | (b1 << 8) | (b2 << 16) | (b3 << 24);
    }
    *(i32x4*)(Xq + (long)row * K + tid * 16) = *(i32x4*)out;
    if (tid == 0) XS[row] = amax / 127.0f;
}

// ---------------- main: 256x256 8-phase i8 GEMM (T2+T3+T4+T5) ----------------
// Same verified schedule as round 5, dtype-swapped: BK=128 i8 (=128B rows, same
// 8x16B-chunk geometry, same chunk^row swizzle, same stage regions/ledger).
// One K-tile = one quant group; per-phase i32 partials folded into fp32 acc
// with the group's column scales (staged via a 9th gload_lds into 2x1KB LDS).
// Ledger (9 issues/tile: q0 B0,B1 | q1 B2,B3 | q2 A0,A2,SC | q3 A1,A3):
// q1 vmcnt(4) drains A1,A3 of this tile; q3 vmcnt(2) leaves newest A1,A3 only.
__global__ __launch_bounds__(512, 2)
void gemm_i8_kernel(const signed char* __restrict__ A,   // M x K i8
                    const signed char* __restrict__ B,   // N x K i8 (q-z)
                    const float* __restrict__ ST,        // G x N w-scales
                    const float* __restrict__ XS,        // M row scales
                    const float* __restrict__ BI,
                    float* __restrict__ Y,
                    int M, int N, int K) {
    extern __shared__ char smem[];   // 131072 + 2048

    const int tid = threadIdx.x;
    const int lane = tid & 63;
    const int wid = tid >> 6;
    const int wr = wid >> 2;     // 0..1 (M)
    const int wc = wid & 3;      // 0..3 (N)
    const int fr = lane & 15;
    const int fq = lane >> 4;

    const int nbn = N / 256;
    const int bid = blockIdx.x;
    const int cpx = gridDim.x >> 3;
    const int wgid = (bid & 7) * cpx + (bid >> 3);   // bijective XCD swizzle
    const int tm = wgid / nbn;
    const int tn = wgid % nbn;
    const long m0 = (long)tm * 256;
    const long n0 = (long)tn * 256;

    // staging: region i covers rows [i*64, i*64+64); wave owns 8 rows (16B each).
    // LDS dest linear; source chunk pre-swizzled: chunk = (lane&7) ^ (row&7).
    const int srow = wid * 8 + (lane >> 3);
    const int schunk = (lane & 7) ^ (lane >> 3);
    const signed char* gA = A + (m0 + srow) * (long)K + schunk * 16;
    const signed char* gB = B + (n0 + srow) * (long)K + schunk * 16;

    auto stageA = [&](int c, int i, int kt) {
        GLOAD_LDS16(gA + (long)i * 64 * K + (long)kt * 128,
                    smem + c * 65536 + i * 8192 + wid * 1024);
    };
    auto stageB = [&](int c, int i, int kt) {
        GLOAD_LDS16(gB + (long)i * 64 * K + (long)kt * 128,
                    smem + c * 65536 + 32768 + i * 8192 + wid * 1024);
    };
    auto stageS = [&](int kt) {   // all waves redundantly: idempotent 1KB row
        GLOAD_LDS16(ST + (long)kt * N + n0 + lane * 4,
                    smem + 131072 + (kt & 1) * 1024);
    };

    const int rswz = fr & 7;    // read-side chunk ^= (row&7); row&7 == fr&7

    f32x4 acc[8][4] = {};
    i32x4 bfr[4][2];            // [nf][ks] — whole K-tile
    i32x4 afr[2][2];            // [ml][ks] — per phase
    const i32x4 zero4 = {0, 0, 0, 0};

    const int NT = K / 128;

    // prologue: tile 0 in steady-state order; leave A1,A3 in flight
    stageB(0, 0, 0); stageB(0, 1, 0); stageB(0, 2, 0); stageB(0, 3, 0);
    stageA(0, 0, 0); stageA(0, 2, 0); stageS(0);
    stageA(0, 1, 0); stageA(0, 3, 0);
    asm volatile("s_waitcnt vmcnt(2)" ::: "memory");
    __builtin_amdgcn_s_barrier();

    for (int t = 0; t < NT - 1; ++t) {
        const int cur = t & 1;
        const char* sA = smem + cur * 65536;
        const char* sB = sA + 32768;
        const char* sS = smem + 131072 + cur * 1024;
        const int nxt = cur ^ 1;
        float s4[4];
#pragma unroll
        for (int q = 0; q < 4; ++q) {
#pragma unroll
            for (int ml = 0; ml < 2; ++ml)
#pragma unroll
                for (int ks = 0; ks < 2; ++ks) {
                    int row = wr * 128 + (2 * q + ml) * 16 + fr;
                    afr[ml][ks] = *(const i32x4*)(sA + row * 128 + ((fq + 4 * ks) ^ rswz) * 16);
                }
            if (q == 0) {
#pragma unroll
                for (int nf = 0; nf < 4; ++nf) {
#pragma unroll
                    for (int ks = 0; ks < 2; ++ks) {
                        int row = wc * 64 + nf * 16 + fr;
                        bfr[nf][ks] = *(const i32x4*)(sB + row * 128 + ((fq + 4 * ks) ^ rswz) * 16);
                    }
                    s4[nf] = *(const float*)(sS + (wc * 64 + nf * 16 + fr) * 4);
                }
            }
            if (q == 0)      { stageB(nxt, 0, t + 1); stageB(nxt, 1, t + 1); }
            else if (q == 1) { stageB(nxt, 2, t + 1); stageB(nxt, 3, t + 1); }
            else if (q == 2) { stageA(nxt, 0, t + 1); stageA(nxt, 2, t + 1); stageS(t + 1); }
            else             { stageA(nxt, 1, t + 1); stageA(nxt, 3, t + 1); }

            if (q == 0) asm volatile("s_waitcnt lgkmcnt(8)" ::: "memory");
            __builtin_amdgcn_s_barrier();
            __builtin_amdgcn_s_setprio(1);
            i32x4 p[2][4];
#pragma unroll
            for (int ml = 0; ml < 2; ++ml)
#pragma unroll
                for (int nf = 0; nf < 4; ++nf)
                    p[ml][nf] = __builtin_amdgcn_mfma_i32_16x16x64_i8(
                        afr[ml][0], bfr[nf][0], zero4, 0, 0, 0);
#pragma unroll
            for (int ml = 0; ml < 2; ++ml)
#pragma unroll
                for (int nf = 0; nf < 4; ++nf)
                    p[ml][nf] = __builtin_amdgcn_mfma_i32_16x16x64_i8(
                        afr[ml][1], bfr[nf][1], p[ml][nf], 0, 0, 0);
            __builtin_amdgcn_s_setprio(0);
            // fold group partials into fp32 acc with per-column W scales
#pragma unroll
            for (int ml = 0; ml < 2; ++ml)
#pragma unroll
                for (int nf = 0; nf < 4; ++nf)
#pragma unroll
                    for (int i = 0; i < 4; ++i)
                        acc[2 * q + ml][nf][i] += (float)p[ml][nf][i] * s4[nf];
            if (q == 1) asm volatile("s_waitcnt vmcnt(4)" ::: "memory");
            if (q == 3) asm volatile("s_waitcnt vmcnt(2)" ::: "memory");
            __builtin_amdgcn_s_barrier();
        }
    }

    // epilogue K-tile: no staging
    {
        const int cur = (NT - 1) & 1;
        const char* sA = smem + cur * 65536;
        const char* sB = sA + 32768;
        const char* sS = smem + 131072 + cur * 1024;
        float s4[4];
#pragma unroll
        for (int q = 0; q < 4; ++q) {
#pragma unroll
            for (int ml = 0; ml < 2; ++ml)
#pragma unroll
                for (int ks = 0; ks < 2; ++ks) {
                    int row = wr * 128 + (2 * q + ml) * 16 + fr;
                    afr[ml][ks] = *(const i32x4*)(sA + row * 128 + ((fq + 4 * ks) ^ rswz) * 16);
                }
            if (q == 0) {
#pragma unroll
                for (int nf = 0; nf < 4; ++nf) {
#pragma unroll
                    for (int ks = 0; ks < 2; ++ks) {
                        int row = wc * 64 + nf * 16 + fr;
                        bfr[nf][ks] = *(const i32x4*)(sB + row * 128 + ((fq + 4 * ks) ^ rswz) * 16);
                    }
                    s4[nf] = *(const float*)(sS + (wc * 64 + nf * 16 + fr) * 4);
                }
            }
            __builtin_amdgcn_s_barrier();
            __builtin_amdgcn_s_setprio(1);
            i32x4 p[2][4];
#pragma unroll
            for (int ml = 0; ml < 2; ++ml)
#pragma unroll
                for (int nf = 0; nf < 4; ++nf)
                    p[ml][nf] = __builtin_amdgcn_mfma_i32_16x16x64_i8(
                        afr[ml][0], bfr[nf][0], zero4, 0, 0, 0);
#pragma unroll
            for (int ml = 0; ml < 2; ++ml)
#pragma unroll
                for (int nf = 0; nf < 4; ++nf)
                    p[ml][nf] = __builtin_amdgcn_mfma_i32_16x16x64_i8(
                        afr[ml][1], bfr[nf][1], p[ml][nf], 0, 0, 0);
            __builtin_amdgcn_s_setprio(0);
#pragma unroll
            for (int ml = 0; ml < 2; ++ml)
#pragma unroll
                for (int nf = 0; nf < 4; ++nf)
#pragma unroll
                    for (int i = 0; i < 4; ++i)
                        acc[2 * q + ml][nf][i] += (float)p[ml][nf][i] * s4[nf];
            if (q == 1) asm volatile("s_waitcnt vmcnt(0)" ::: "memory");
            __builtin_amdgcn_s_barrier();
        }
    }

    // C-write: col=lane&15, row=4*(lane>>4)+i [m89/m91]; fold X row-scale + bias
#pragma unroll
    for (int nf = 0; nf < 4; ++nf) {
        const long col = n0 + wc * 64 + nf * 16 + fr;
        const float bv = BI[col];
#pragma unroll
        for (int m = 0; m < 8; ++m) {
            const long rbase = m0 + wr * 128 + m * 16 + 4 * fq;
#pragma unroll
            for (int i = 0; i < 4; ++i)
                Y[(rbase + i) * N + col] = acc[m][nf][i] * XS[rbase + i] + bv;
        }
    }
}

// ---------------- fallback: fused fp32 kernel (verified round 2) ----------------
#define BM 128
#define BN 128
#define BK 64
#define PK 72

__global__ void gptq_gemm_fallback(const float* __restrict__ X,
                                   const int* __restrict__ QW,
                                   const float* __restrict__ SC,
                                   const int* __restrict__ ZR,
                                   const float* __restrict__ BI,
                                   float* __restrict__ Y,
                                   int M, int N, int K, int G) {
    __shared__ __align__(16) short As[BM * PK];
    __shared__ __align__(16) short Bs[BN * PK];

    const int tid = threadIdx.x;
    const int nbm = M / BM;
    const int bid = blockIdx.x;
    const int cpx = gridDim.x >> 3;
    const int wgid = (bid & 7) * cpx + (bid >> 3);
    const int tm = wgid % nbm;
    const int tn = wgid / nbm;
    const long m0 = (long)tm * BM;
    const long n0 = (long)tn * BN;
    const int Kp = K >> 1;

    const int lane = tid & 63;
    const int wid = tid >> 6;
    const int wr = wid >> 1;
    const int wc = wid & 1;
    const int fr = lane & 15;
    const int fq = lane >> 4;

    int srow[4], sq[4];
#pragma unroll
    for (int c = 0; c < 4; ++c) {
        int w = tid + 256 * c;
        srow[c] = w >> 3;
        sq[c] = w & 7;
    }

    f32x4 acc[4][4] = {};
    const int NT = K / BK;

    for (int kt = 0; kt < NT; ++kt) {
        const int g = (kt * BK) / GS;
        f32x4 a0[4], a1[4];
        i32x4 b4[4];
        float sc_r[4], zr_r[4];
#pragma unroll
        for (int c = 0; c < 4; ++c) {
            const float* pa = X + (m0 + srow[c]) * K + kt * BK + 8 * sq[c];
            a0[c] = *(const f32x4*)pa;
            a1[c] = *(const f32x4*)(pa + 4);
            const int* pb = QW + (n0 + srow[c]) * Kp + kt * (BK / 2) + 4 * sq[c];
            b4[c] = *(const i32x4*)pb;
            sc_r[c] = SC[(n0 + srow[c]) * G + g];
            zr_r[c] = (float)ZR[(n0 + srow[c]) * G + g];
        }
        __syncthreads();
#pragma unroll
        for (int c = 0; c < 4; ++c) {
            bf16x8 av;
#pragma unroll
            for (int i = 0; i < 4; ++i) av[i] = f2bf(a0[c][i]);
#pragma unroll
            for (int i = 0; i < 4; ++i) av[4 + i] = f2bf(a1[c][i]);
            *(bf16x8*)(As + srow[c] * PK + 8 * sq[c]) = av;
            bf16x8 bv;
#pragma unroll
            for (int j = 0; j < 4; ++j) {
                int v = b4[c][j];
                bv[2 * j]     = f2bf(((float)(v & 15) - zr_r[c]) * sc_r[c]);
                bv[2 * j + 1] = f2bf(((float)((v >> 4) & 15) - zr_r[c]) * sc_r[c]);
            }
            *(bf16x8*)(Bs + srow[c] * PK + 8 * sq[c]) = bv;
        }
        __syncthreads();
#pragma unroll
        for (int kk = 0; kk < BK; kk += 32) {
            bf16x8 a[4], b[4];
#pragma unroll
            for (int mf = 0; mf < 4; ++mf)
                a[mf] = *(const bf16x8*)(As + (wr * 64 + mf * 16 + fr) * PK + kk + 8 * fq);
#pragma unroll
            for (int nf = 0; nf < 4; ++nf)
                b[nf] = *(const bf16x8*)(Bs + (wc * 64 + nf * 16 + fr) * PK + kk + 8 * fq);
#pragma unroll
            for (int mf = 0; mf < 4; ++mf)
#pragma unroll
                for (int nf = 0; nf < 4; ++nf)
                    acc[mf][nf] = __builtin_amdgcn_mfma_f32_16x16x32_bf16(
                        a[mf], b[nf], acc[mf][nf], 0, 0, 0);
        }
    }

#pragma unroll
    for (int nf = 0; nf < 4; ++nf) {
        const long col = n0 + wc * 64 + nf * 16 + fr;
        const float bias_v = BI[col];
#pragma unroll
        for (int mf = 0; mf < 4; ++mf) {
            const long rbase = m0 + wr * 64 + mf * 16 + 4 * fq;
#pragma unroll
            for (int i = 0; i < 4; ++i)
                Y[(rbase + i) * N + col] = acc[mf][nf][i] + bias_v;
        }
    }
}

extern "C" void kernel_launch(void* const* d_in, const int* in_sizes, int n_in,
                              void* d_out, int out_size, void* d_ws, size_t ws_size,
                              hipStream_t stream) {
    const float* X = (const float*)d_in[0];
    const int* QW = (const int*)d_in[1];
    const float* SC = (const float*)d_in[2];
    const int* ZR = (const int*)d_in[3];
    const float* BI = (const float*)d_in[4];
    float* Y = (float*)d_out;

    const int N = in_sizes[4];          // 4096
    const int G = in_sizes[2] / N;      // 32
    const int K = G * GS;               // 4096
    const int M = in_sizes[0] / K;      // 8192

    const size_t needW8 = (size_t)N * K;            // int8 W
    const size_t needXq = (size_t)M * K;            // int8 X
    const size_t needXS = (size_t)M * 4;
    const size_t needST = (size_t)G * N * 4;
    const size_t need = needW8 + needXq + needXS + needST;

    if (ws_size >= need) {
        signed char* W8 = (signed char*)d_ws;
        signed char* Xq = W8 + needW8;
        float* XS = (float*)(Xq + needXq);
        float* ST = XS + M;

        hipLaunchKernelGGL(quant_w_kernel, dim3((N * (K / 32)) / 256), dim3(256),
                           0, stream, QW, ZR, W8, K, G);
        hipLaunchKernelGGL(sct_kernel, dim3((N * G) / 256), dim3(256),
                           0, stream, SC, ST, N, G);
        hipLaunchKernelGGL(quant_x_kernel, dim3(M), dim3(256),
                           0, stream, X, Xq, XS, K);

        (void)hipFuncSetAttribute((const void*)gemm_i8_kernel,
                                  hipFuncAttributeMaxDynamicSharedMemorySize, 133120);
        const int grid = (M / 256) * (N / 256);   // 512, % 8 == 0
        hipLaunchKernelGGL(gemm_i8_kernel, dim3(grid), dim3(512), 133120, stream,
                           Xq, W8, ST, XS, BI, Y, M, N, K);
    } else {
        const int grid = (M / BM) * (N / BN);
        hipLaunchKernelGGL(gptq_gemm_fallback, dim3(grid), dim3(256), 0, stream,
                           X, QW, SC, ZR, BI, Y, M, N, K, G);
    }
}

// Round 7
// 185.878 us; speedup vs baseline: 6.3312x; 1.2998x over previous
//
#include <hip/hip_runtime.h>
#include <hip/hip_bf16.h>

typedef __attribute__((ext_vector_type(4))) float f32x4;
typedef __attribute__((ext_vector_type(8))) short bf16x8;
typedef __attribute__((ext_vector_type(4))) int i32x4;

#define GS 128

#define GLOAD_LDS16(g, l)                                                        \
    __builtin_amdgcn_global_load_lds(                                            \
        (const __attribute__((address_space(1))) void*)(g),                      \
        (__attribute__((address_space(3))) void*)(l), 16, 0, 0)

__device__ __forceinline__ short f2bf(float f) {
    union { float f; unsigned u; } v; v.f = f;
    unsigned r = v.u + 0x7fffu + ((v.u >> 16) & 1u);
    return (short)(r >> 16);
}

// ---------------- prep: per-row W requant -> int8 with per-row scale ----------
// w[o,k] = (q-z[o,g])*s[o,g]; WS[o] = max_k |w| / 127; W8 = rint(w / WS[o]).
// One block per output row o; 256 threads x 16 weights (16 | GS so one group).
__global__ void requant_w_kernel(const int* __restrict__ QW,
                                 const float* __restrict__ SC,
                                 const int* __restrict__ ZR,
                                 signed char* __restrict__ W8,
                                 float* __restrict__ WS, int K, int G) {
    const int o = blockIdx.x;
    const int tid = threadIdx.x;             // 0..255, 16 weights each
    const int lane = tid & 63;
    const int wid = tid >> 6;
    const int g = tid / 8;                   // (tid*16)/128
    const float s = SC[(long)o * G + g];
    const float z = (float)ZR[(long)o * G + g];
    const int* p = QW + (long)o * (K / 2) + tid * 8;
    int v[8];
#pragma unroll
    for (int j = 0; j < 8; ++j) v[j] = p[j];
    float w[16];
#pragma unroll
    for (int j = 0; j < 8; ++j) {
        w[2 * j]     = ((float)(v[j] & 15) - z) * s;
        w[2 * j + 1] = ((float)((v[j] >> 4) & 15) - z) * s;
    }
    float am = 0.f;
#pragma unroll
    for (int j = 0; j < 16; ++j) am = fmaxf(am, fabsf(w[j]));
#pragma unroll
    for (int off = 32; off >= 1; off >>= 1) am = fmaxf(am, __shfl_xor(am, off));
    __shared__ float red[4];
    if (lane == 0) red[wid] = am;
    __syncthreads();
    float wmax = fmaxf(fmaxf(red[0], red[1]), fmaxf(red[2], red[3]));
    wmax = fmaxf(wmax, 1e-30f);
    const float qs = 127.0f / wmax;
    int out[4];
#pragma unroll
    for (int j = 0; j < 4; ++j) {
        int b0 = ((int)rintf(w[4 * j]     * qs)) & 255;
        int b1 = ((int)rintf(w[4 * j + 1] * qs)) & 255;
        int b2 = ((int)rintf(w[4 * j + 2] * qs)) & 255;
        int b3 = ((int)rintf(w[4 * j + 3] * qs)) & 255;
        out[j] = b0 | (b1 << 8) | (b2 << 16) | (b3 << 24);
    }
    *(i32x4*)(W8 + (long)o * K + tid * 16) = *(i32x4*)out;
    if (tid == 0) WS[o] = wmax / 127.0f;
}

// ---------------- prep: per-row dynamic int8 quant of X ----------------
__global__ void quant_x_kernel(const float* __restrict__ X,
                               signed char* __restrict__ Xq,
                               float* __restrict__ XS, int K) {
    const int row = blockIdx.x;
    const int tid = threadIdx.x;             // 256, each 16 floats
    const int lane = tid & 63;
    const int wid = tid >> 6;
    const float* px = X + (long)row * K + tid * 16;
    f32x4 v[4];
#pragma unroll
    for (int j = 0; j < 4; ++j) v[j] = *(const f32x4*)(px + j * 4);
    float am = 0.f;
#pragma unroll
    for (int j = 0; j < 4; ++j)
#pragma unroll
        for (int i = 0; i < 4; ++i) am = fmaxf(am, fabsf(v[j][i]));
#pragma unroll
    for (int off = 32; off >= 1; off >>= 1) am = fmaxf(am, __shfl_xor(am, off));
    __shared__ float red[4];
    if (lane == 0) red[wid] = am;
    __syncthreads();
    float amax = fmaxf(fmaxf(red[0], red[1]), fmaxf(red[2], red[3]));
    amax = fmaxf(amax, 1e-30f);
    const float qs = 127.0f / amax;
    int out[4];
#pragma unroll
    for (int j = 0; j < 4; ++j) {
        int b0 = ((int)rintf(v[j][0] * qs)) & 255;
        int b1 = ((int)rintf(v[j][1] * qs)) & 255;
        int b2 = ((int)rintf(v[j][2] * qs)) & 255;
        int b3 = ((int)rintf(v[j][3] * qs)) & 255;
        out[j] = b0 | (b1 << 8) | (b2 << 16) | (b3 << 24);
    }
    *(i32x4*)(Xq + (long)row * K + tid * 16) = *(i32x4*)out;
    if (tid == 0) XS[row] = amax / 127.0f;
}

// ---------------- main: 256x256 8-phase pure-i8 GEMM (T2+T3+T4+T5) ------------
// Round-5-verified schedule, i8 dtype: BK=128 (=128B rows, same 8x16B-chunk
// geometry, same chunk^row swizzle). Single i32 accumulator chain over all K;
// scales fold once in epilogue. Ledger (8 issues/tile, q0 B0,B1 | q1 B2,B3 |
// q2 A0,A2 | q3 A1,A3): q1 vmcnt(4) drains this tile's A1,A3; q3 vmcnt(2)
// leaves only the newest A1,A3 in flight. Never vmcnt(0) in the main loop.
__global__ __launch_bounds__(512, 2)
void gemm_i8_kernel(const signed char* __restrict__ A,   // M x K i8
                    const signed char* __restrict__ B,   // N x K i8
                    const float* __restrict__ WS,        // N w row-scales
                    const float* __restrict__ XS,        // M x row-scales
                    const float* __restrict__ BI,
                    float* __restrict__ Y,
                    int M, int N, int K) {
    extern __shared__ char smem[];   // 131072

    const int tid = threadIdx.x;
    const int lane = tid & 63;
    const int wid = tid >> 6;
    const int wr = wid >> 2;     // 0..1 (M)
    const int wc = wid & 3;      // 0..3 (N)
    const int fr = lane & 15;
    const int fq = lane >> 4;

    const int nbn = N / 256;
    const int bid = blockIdx.x;
    const int cpx = gridDim.x >> 3;
    const int wgid = (bid & 7) * cpx + (bid >> 3);   // bijective XCD swizzle
    const int tm = wgid / nbn;
    const int tn = wgid % nbn;
    const long m0 = (long)tm * 256;
    const long n0 = (long)tn * 256;

    // staging: region i covers rows [i*64, i*64+64); wave owns 8 rows (16B each).
    // LDS dest linear; source chunk pre-swizzled: chunk = (lane&7) ^ (row&7).
    const int srow = wid * 8 + (lane >> 3);
    const int schunk = (lane & 7) ^ (lane >> 3);
    const signed char* gA = A + (m0 + srow) * (long)K + schunk * 16;
    const signed char* gB = B + (n0 + srow) * (long)K + schunk * 16;

    auto stageA = [&](int c, int i, int kt) {
        GLOAD_LDS16(gA + (long)i * 64 * K + (long)kt * 128,
                    smem + c * 65536 + i * 8192 + wid * 1024);
    };
    auto stageB = [&](int c, int i, int kt) {
        GLOAD_LDS16(gB + (long)i * 64 * K + (long)kt * 128,
                    smem + c * 65536 + 32768 + i * 8192 + wid * 1024);
    };

    const int rswz = fr & 7;    // read-side chunk ^= (row&7); row&7 == fr&7

    i32x4 acc[8][4] = {};
    i32x4 bfr[4][2];            // [nf][ks] — whole K-tile
    i32x4 afr[2][2];            // [ml][ks] — per phase

    const int NT = K / 128;

    // prologue: tile 0 in steady-state order; leave A1,A3 in flight (needed q2)
    stageB(0, 0, 0); stageB(0, 1, 0); stageB(0, 2, 0); stageB(0, 3, 0);
    stageA(0, 0, 0); stageA(0, 2, 0);
    stageA(0, 1, 0); stageA(0, 3, 0);
    asm volatile("s_waitcnt vmcnt(2)" ::: "memory");
    __builtin_amdgcn_s_barrier();

    for (int t = 0; t < NT - 1; ++t) {
        const int cur = t & 1;
        const char* sA = smem + cur * 65536;
        const char* sB = sA + 32768;
        const int nxt = cur ^ 1;
#pragma unroll
        for (int q = 0; q < 4; ++q) {
#pragma unroll
            for (int ml = 0; ml < 2; ++ml)
#pragma unroll
                for (int ks = 0; ks < 2; ++ks) {
                    int row = wr * 128 + (2 * q + ml) * 16 + fr;
                    afr[ml][ks] = *(const i32x4*)(sA + row * 128 + ((fq + 4 * ks) ^ rswz) * 16);
                }
            if (q == 0) {
#pragma unroll
                for (int nf = 0; nf < 4; ++nf)
#pragma unroll
                    for (int ks = 0; ks < 2; ++ks) {
                        int row = wc * 64 + nf * 16 + fr;
                        bfr[nf][ks] = *(const i32x4*)(sB + row * 128 + ((fq + 4 * ks) ^ rswz) * 16);
                    }
            }
            if (q == 0)      { stageB(nxt, 0, t + 1); stageB(nxt, 1, t + 1); }
            else if (q == 1) { stageB(nxt, 2, t + 1); stageB(nxt, 3, t + 1); }
            else if (q == 2) { stageA(nxt, 0, t + 1); stageA(nxt, 2, t + 1); }
            else             { stageA(nxt, 1, t + 1); stageA(nxt, 3, t + 1); }

            if (q == 0) asm volatile("s_waitcnt lgkmcnt(8)" ::: "memory");
            __builtin_amdgcn_s_barrier();
            __builtin_amdgcn_s_setprio(1);
#pragma unroll
            for (int ml = 0; ml < 2; ++ml)
#pragma unroll
                for (int nf = 0; nf < 4; ++nf)
                    acc[2 * q + ml][nf] = __builtin_amdgcn_mfma_i32_16x16x64_i8(
                        afr[ml][0], bfr[nf][0], acc[2 * q + ml][nf], 0, 0, 0);
#pragma unroll
            for (int ml = 0; ml < 2; ++ml)
#pragma unroll
                for (int nf = 0; nf < 4; ++nf)
                    acc[2 * q + ml][nf] = __builtin_amdgcn_mfma_i32_16x16x64_i8(
                        afr[ml][1], bfr[nf][1], acc[2 * q + ml][nf], 0, 0, 0);
            __builtin_amdgcn_s_setprio(0);
            if (q == 1) asm volatile("s_waitcnt vmcnt(4)" ::: "memory");
            if (q == 3) asm volatile("s_waitcnt vmcnt(2)" ::: "memory");
            __builtin_amdgcn_s_barrier();
        }
    }

    // epilogue K-tile: no staging
    {
        const int cur = (NT - 1) & 1;
        const char* sA = smem + cur * 65536;
        const char* sB = sA + 32768;
#pragma unroll
        for (int q = 0; q < 4; ++q) {
#pragma unroll
            for (int ml = 0; ml < 2; ++ml)
#pragma unroll
                for (int ks = 0; ks < 2; ++ks) {
                    int row = wr * 128 + (2 * q + ml) * 16 + fr;
                    afr[ml][ks] = *(const i32x4*)(sA + row * 128 + ((fq + 4 * ks) ^ rswz) * 16);
                }
            if (q == 0) {
#pragma unroll
                for (int nf = 0; nf < 4; ++nf)
#pragma unroll
                    for (int ks = 0; ks < 2; ++ks) {
                        int row = wc * 64 + nf * 16 + fr;
                        bfr[nf][ks] = *(const i32x4*)(sB + row * 128 + ((fq + 4 * ks) ^ rswz) * 16);
                    }
            }
            __builtin_amdgcn_s_barrier();
            __builtin_amdgcn_s_setprio(1);
#pragma unroll
            for (int ml = 0; ml < 2; ++ml)
#pragma unroll
                for (int nf = 0; nf < 4; ++nf)
                    acc[2 * q + ml][nf] = __builtin_amdgcn_mfma_i32_16x16x64_i8(
                        afr[ml][0], bfr[nf][0], acc[2 * q + ml][nf], 0, 0, 0);
#pragma unroll
            for (int ml = 0; ml < 2; ++ml)
#pragma unroll
                for (int nf = 0; nf < 4; ++nf)
                    acc[2 * q + ml][nf] = __builtin_amdgcn_mfma_i32_16x16x64_i8(
                        afr[ml][1], bfr[nf][1], acc[2 * q + ml][nf], 0, 0, 0);
            __builtin_amdgcn_s_setprio(0);
            if (q == 1) asm volatile("s_waitcnt vmcnt(0)" ::: "memory");
            __builtin_amdgcn_s_barrier();
        }
    }

    // C-write: col=lane&15, row=4*(lane>>4)+i [m89/m91]; y = i32*XS[m]*WS[o]+b
#pragma unroll
    for (int nf = 0; nf < 4; ++nf) {
        const long col = n0 + wc * 64 + nf * 16 + fr;
        const float ws = WS[col];
        const float bv = BI[col];
#pragma unroll
        for (int m = 0; m < 8; ++m) {
            const long rbase = m0 + wr * 128 + m * 16 + 4 * fq;
#pragma unroll
            for (int i = 0; i < 4; ++i)
                Y[(rbase + i) * N + col] =
                    (float)acc[m][nf][i] * (XS[rbase + i] * ws) + bv;
        }
    }
}

// ---------------- fallback: fused fp32 kernel (verified round 2) ----------------
#define BM 128
#define BN 128
#define BK 64
#define PK 72

__global__ void gptq_gemm_fallback(const float* __restrict__ X,
                                   const int* __restrict__ QW,
                                   const float* __restrict__ SC,
                                   const int* __restrict__ ZR,
                                   const float* __restrict__ BI,
                                   float* __restrict__ Y,
                                   int M, int N, int K, int G) {
    __shared__ __align__(16) short As[BM * PK];
    __shared__ __align__(16) short Bs[BN * PK];

    const int tid = threadIdx.x;
    const int nbm = M / BM;
    const int bid = blockIdx.x;
    const int cpx = gridDim.x >> 3;
    const int wgid = (bid & 7) * cpx + (bid >> 3);
    const int tm = wgid % nbm;
    const int tn = wgid / nbm;
    const long m0 = (long)tm * BM;
    const long n0 = (long)tn * BN;
    const int Kp = K >> 1;

    const int lane = tid & 63;
    const int wid = tid >> 6;
    const int wr = wid >> 1;
    const int wc = wid & 1;
    const int fr = lane & 15;
    const int fq = lane >> 4;

    int srow[4], sq[4];
#pragma unroll
    for (int c = 0; c < 4; ++c) {
        int w = tid + 256 * c;
        srow[c] = w >> 3;
        sq[c] = w & 7;
    }

    f32x4 acc[4][4] = {};
    const int NT = K / BK;

    for (int kt = 0; kt < NT; ++kt) {
        const int g = (kt * BK) / GS;
        f32x4 a0[4], a1[4];
        i32x4 b4[4];
        float sc_r[4], zr_r[4];
#pragma unroll
        for (int c = 0; c < 4; ++c) {
            const float* pa = X + (m0 + srow[c]) * K + kt * BK + 8 * sq[c];
            a0[c] = *(const f32x4*)pa;
            a1[c] = *(const f32x4*)(pa + 4);
            const int* pb = QW + (n0 + srow[c]) * Kp + kt * (BK / 2) + 4 * sq[c];
            b4[c] = *(const i32x4*)pb;
            sc_r[c] = SC[(n0 + srow[c]) * G + g];
            zr_r[c] = (float)ZR[(n0 + srow[c]) * G + g];
        }
        __syncthreads();
#pragma unroll
        for (int c = 0; c < 4; ++c) {
            bf16x8 av;
#pragma unroll
            for (int i = 0; i < 4; ++i) av[i] = f2bf(a0[c][i]);
#pragma unroll
            for (int i = 0; i < 4; ++i) av[4 + i] = f2bf(a1[c][i]);
            *(bf16x8*)(As + srow[c] * PK + 8 * sq[c]) = av;
            bf16x8 bv;
#pragma unroll
            for (int j = 0; j < 4; ++j) {
                int v = b4[c][j];
                bv[2 * j]     = f2bf(((float)(v & 15) - zr_r[c]) * sc_r[c]);
                bv[2 * j + 1] = f2bf(((float)((v >> 4) & 15) - zr_r[c]) * sc_r[c]);
            }
            *(bf16x8*)(Bs + srow[c] * PK + 8 * sq[c]) = bv;
        }
        __syncthreads();
#pragma unroll
        for (int kk = 0; kk < BK; kk += 32) {
            bf16x8 a[4], b[4];
#pragma unroll
            for (int mf = 0; mf < 4; ++mf)
                a[mf] = *(const bf16x8*)(As + (wr * 64 + mf * 16 + fr) * PK + kk + 8 * fq);
#pragma unroll
            for (int nf = 0; nf < 4; ++nf)
                b[nf] = *(const bf16x8*)(Bs + (wc * 64 + nf * 16 + fr) * PK + kk + 8 * fq);
#pragma unroll
            for (int mf = 0; mf < 4; ++mf)
#pragma unroll
                for (int nf = 0; nf < 4; ++nf)
                    acc[mf][nf] = __builtin_amdgcn_mfma_f32_16x16x32_bf16(
                        a[mf], b[nf], acc[mf][nf], 0, 0, 0);
        }
    }

#pragma unroll
    for (int nf = 0; nf < 4; ++nf) {
        const long col = n0 + wc * 64 + nf * 16 + fr;
        const float bias_v = BI[col];
#pragma unroll
        for (int mf = 0; mf < 4; ++mf) {
            const long rbase = m0 + wr * 64 + mf * 16 + 4 * fq;
#pragma unroll
            for (int i = 0; i < 4; ++i)
                Y[(rbase + i) * N + col] = acc[mf][nf][i] + bias_v;
        }
    }
}

extern "C" void kernel_launch(void* const* d_in, const int* in_sizes, int n_in,
                              void* d_out, int out_size, void* d_ws, size_t ws_size,
                              hipStream_t stream) {
    const float* X = (const float*)d_in[0];
    const int* QW = (const int*)d_in[1];
    const float* SC = (const float*)d_in[2];
    const int* ZR = (const int*)d_in[3];
    const float* BI = (const float*)d_in[4];
    float* Y = (float*)d_out;

    const int N = in_sizes[4];          // 4096
    const int G = in_sizes[2] / N;      // 32
    const int K = G * GS;               // 4096
    const int M = in_sizes[0] / K;      // 8192

    const size_t needW8 = (size_t)N * K;            // int8 W
    const size_t needXq = (size_t)M * K;            // int8 X
    const size_t needXS = (size_t)M * 4;
    const size_t needWS = (size_t)N * 4;
    const size_t need = needW8 + needXq + needXS + needWS;

    if (ws_size >= need) {
        signed char* W8 = (signed char*)d_ws;
        signed char* Xq = W8 + needW8;
        float* XS = (float*)(Xq + needXq);
        float* WS = XS + M;

        hipLaunchKernelGGL(requant_w_kernel, dim3(N), dim3(256), 0, stream,
                           QW, SC, ZR, W8, WS, K, G);
        hipLaunchKernelGGL(quant_x_kernel, dim3(M), dim3(256), 0, stream,
                           X, Xq, XS, K);

        (void)hipFuncSetAttribute((const void*)gemm_i8_kernel,
                                  hipFuncAttributeMaxDynamicSharedMemorySize, 131072);
        const int grid = (M / 256) * (N / 256);   // 512, % 8 == 0
        hipLaunchKernelGGL(gemm_i8_kernel, dim3(grid), dim3(512), 131072, stream,
                           Xq, W8, WS, XS, BI, Y, M, N, K);
    } else {
        const int grid = (M / BM) * (N / BN);
        hipLaunchKernelGGL(gptq_gemm_fallback, dim3(grid), dim3(256), 0, stream,
                           X, QW, SC, ZR, BI, Y, M, N, K, G);
    }
}